// Round 13
// baseline (817.131 us; speedup 1.0000x reference)
//
#include <hip/hip_runtime.h>

#define B_  128
#define T_  256
#define D_  256
#define U_  256
#define TU  768      // 3*U
#define TC  64       // timestep chunk
#define NC  (T_/TC)  // 4 chunks

__device__ __forceinline__ float sigm(float x) { return 1.f / (1.f + __expf(-x)); }

// tanh via __expf: tanh(x) = 1 - 2/(e^{2x}+1). (absmax unchanged since R2)
__device__ __forceinline__ float tanh_fast(float x) {
    float e = __expf(2.f * x);
    return 1.f - 2.f / (e + 1.f);
}

// direct cubic B-spline eval: grid cells [g_j, g_j+0.4), g_j = -2.2 + 0.4*j, j=0..10
// nonzero basis m = j-3..j (clipped to 0..7); coeffs at ksw_lds[u*9 + m]
__device__ __forceinline__ float spline_eval(float x, const float* __restrict__ ksw_lds, int u) {
    float xc = (x + 2.2f) * 2.5f;
    float fj = floorf(xc);
    int   j  = (int)fj;
    float tl = xc - fj;
    float t2 = tl * tl, t3 = t2 * tl;
    float om = 1.f - tl;
    const float S = 1.f / 6.f;
    float w0 = om * om * om * S;                            // m = j-3
    float w1 = (3.f * t3 - 6.f * t2 + 4.f) * S;             // m = j-2
    float w2 = (-3.f * t3 + 3.f * t2 + 3.f * tl + 1.f) * S; // m = j-1
    float w3 = t3 * S;                                      // m = j
    bool  v  = (j >= 0) && (j <= 10);
    float r  = 0.f;
#pragma unroll
    for (int k = 0; k < 4; ++k) {
        int   m  = j - 3 + k;
        bool  ok = v && (m >= 0) && (m <= 7);
        int   mc = min(max(m, 0), 7);
        float wk = (k == 0) ? w0 : (k == 1) ? w1 : (k == 2) ? w2 : w3;
        float cf = ksw_lds[u * 9 + mc];
        r += ok ? wk * cf : 0.f;
    }
    return r;
}

// Barrier with LDS-only drain: lgkmcnt(0) guarantees all LDS writes visible,
// but in-flight VMEM (xh sentinel stores, A/X prefetch loads) stays counted
// across the barrier (T4 pattern). The xh store needs NO ordering -- its
// sentinel tag makes the data self-validating at the consumer; loads are
// waited at their use sites by compiler-inserted vmcnt. Single asm block with
// memory clobber pins compiler code motion on both sides.
#define BAR_LGKM() asm volatile("s_waitcnt lgkmcnt(0)\ns_barrier" ::: "memory")

// ---------------- K0: zero recurrent state + poison xh tags ----------------
__global__ void k0_init(float* __restrict__ wh, float* __restrict__ wc,
                        float* __restrict__ wsub, float* __restrict__ xh) {
    int i = blockIdx.x * 256 + threadIdx.x;          // grid 128 -> 32768
    wh[i] = 0.f;
    wc[i] = 0.f;
    ((int*)xh)[i]         = 1;
    ((int*)xh)[i + 32768] = 1;
    if (i < 3 * B_) wsub[i] = 0.f;
}

// ---------------- K1: A[b][tl][j] = x[b, t0+tl, :] @ kernel + bias ----------------
// 64x128 / 256 thr / 4x8 acc, double-buffered (R12, 54 us). Model: LDS-return-BW
// bound at 384 B/output -> ~46 us floor; geometry alternatives violate occupancy
// (R11: 1 wave/SIMD = 80 us) or balance (R7: 1 block/CU = 65 us). Parked.
__global__ __launch_bounds__(256) void k1_gemm(const float* __restrict__ X,
                                               const float* __restrict__ Km,
                                               const float* __restrict__ bias,
                                               float* __restrict__ A, int t0) {
    __shared__ float Xs[2][16][68];    // 8.7 KB
    __shared__ float Ks[2][16][132];   // 16.9 KB
    const int tid = threadIdx.x;
    const int bm  = blockIdx.x * 64;
    const int bn  = blockIdx.y * 128;

    const int ty = tid >> 4, tx = tid & 15;
    const int m0 = ty * 4, n0 = tx * 4;

    const int xr = tid & 63, kq = (tid >> 6) * 4;
    const int rr = bm + xr;
    const float* xrow = X + (size_t)((rr >> 6) * T_ + t0 + (rr & 63)) * D_;

    const int kr = tid >> 4, nq = (tid & 15) * 8;
    const float* krow = Km + (size_t)kr * TU + bn + nq;

    {
        float4 xv  = *(const float4*)(xrow + kq);
        float4 kv0 = *(const float4*)(krow);
        float4 kv1 = *(const float4*)(krow + 4);
        Xs[0][kq + 0][xr] = xv.x; Xs[0][kq + 1][xr] = xv.y;
        Xs[0][kq + 2][xr] = xv.z; Xs[0][kq + 3][xr] = xv.w;
        *(float4*)&Ks[0][kr][nq]     = kv0;
        *(float4*)&Ks[0][kr][nq + 4] = kv1;
    }
    __syncthreads();

    float acc[4][8] = {};
    for (int kb = 0; kb < 16; ++kb) {
        const int cur = kb & 1;
        float4 xv, kv0, kv1;
        if (kb + 1 < 16) {
            const float* xp = xrow + (kb + 1) * 16 + kq;
            const float* kp = krow + (size_t)(kb + 1) * 16 * TU;
            xv  = *(const float4*)(xp);
            kv0 = *(const float4*)(kp);
            kv1 = *(const float4*)(kp + 4);
        }
#pragma unroll
        for (int k = 0; k < 16; ++k) {
            float4 av = *(float4*)&Xs[cur][k][m0];
            float4 b0 = *(float4*)&Ks[cur][k][n0];
            float4 b1 = *(float4*)&Ks[cur][k][64 + n0];
            float a[4]  = {av.x, av.y, av.z, av.w};
            float bb[8] = {b0.x, b0.y, b0.z, b0.w, b1.x, b1.y, b1.z, b1.w};
#pragma unroll
            for (int i = 0; i < 4; ++i)
#pragma unroll
                for (int j = 0; j < 8; ++j)
                    acc[i][j] = fmaf(a[i], bb[j], acc[i][j]);
        }
        if (kb + 1 < 16) {
            const int nxt = cur ^ 1;
            Xs[nxt][kq + 0][xr] = xv.x; Xs[nxt][kq + 1][xr] = xv.y;
            Xs[nxt][kq + 2][xr] = xv.z; Xs[nxt][kq + 3][xr] = xv.w;
            *(float4*)&Ks[nxt][kr][nq]     = kv0;
            *(float4*)&Ks[nxt][kr][nq + 4] = kv1;
            __syncthreads();
        }
    }
    float4 bv0 = *(const float4*)(bias + bn + n0);
    float4 bv1 = *(const float4*)(bias + bn + 64 + n0);
#pragma unroll
    for (int i = 0; i < 4; ++i) {
        float4 o0, o1;
        o0.x = acc[i][0] + bv0.x; o0.y = acc[i][1] + bv0.y;
        o0.z = acc[i][2] + bv0.z; o0.w = acc[i][3] + bv0.w;
        o1.x = acc[i][4] + bv1.x; o1.y = acc[i][5] + bv1.y;
        o1.z = acc[i][6] + bv1.z; o1.w = acc[i][7] + bv1.w;
        *(float4*)(A + (size_t)(bm + m0 + i) * TU + bn + n0)      = o0;
        *(float4*)(A + (size_t)(bm + m0 + i) * TU + bn + 64 + n0) = o1;
    }
}

// ---------------- K2: pair-split recurrence, R stationary in regs ----------------
// R9 schedule (141 us, verified 3x) + ROUND 13: the two in-loop barriers become
// lgkmcnt-only (BAR_LGKM). __syncthreads' implicit vmcnt(0) drain was making the
// pstate waves (last to arrive: they compute gates) wait ~500-700cyc for L3
// store-acks of their 64 xh sentinel stores at syncCA, and for freshly-issued
// A-prefetch loads at syncB -- neither is semantically required (sentinel data
// self-validates; loads are waited at use). Do NOT reorder phases (R10 lesson).
__global__ __launch_bounds__(512, 2)
void k2_rec(const float* __restrict__ A,
            const float* __restrict__ X,
            const float* __restrict__ R,
            const float* __restrict__ stk,
            const float* __restrict__ strk,
            const float* __restrict__ aggw,
            const float* __restrict__ aggb,
            const float* __restrict__ kbw,
            const float* __restrict__ ksw,
            float* __restrict__ out,
            float* __restrict__ ws_h,
            float* __restrict__ ws_c,
            float* __restrict__ ws_sub,
            float* __restrict__ xh,    // [B][2][256], sentinel-tagged
            int t0) {
    __shared__ float hs[256];
    __shared__ float xs[256];
    __shared__ float zred[8][64][3];
    __shared__ float kred[768];
    __shared__ float so_l[3];
    __shared__ float subs[3];
    __shared__ float st2[6];
    __shared__ float hhist[TC][128];        // 32 KB h history -> epilogue bulk write
    __shared__ float ksw_lds[768 * 9];

    const int tid  = threadIdx.x;
    const int lane = tid & 63;
    const int w    = tid >> 6;
    const int p    = w & 3;
    const int c    = ((w >> 2) << 6) | lane;   // 0..127
    const int b    = blockIdx.x & 127;
    const int r    = blockIdx.x >> 7;
    const int ui   = r * 128 + c;              // global output-unit index
    const bool pstate = (p == 0);              // waves 0 and 4 hold gate state

    // ---- stationary R fragment (lives in unified VGPR/AGPR file) ----
    float Rf[3][64];
#pragma unroll
    for (int g = 0; g < 3; ++g)
#pragma unroll
        for (int uu = 0; uu < 64; ++uu)
            Rf[g][uu] = R[(size_t)(p * 64 + uu) * TU + g * 256 + ui];

    // ---- KAN duties: u0 = tid for ALL; u1 + x-prefetch on waves 1,2,3,5 ----
    const int s0 = tid >> 8, d0 = tid & 255;
    const float skx0 = strk[s0 * 512 + d0];
    const float skh0 = strk[s0 * 512 + 256 + d0];
    const float bw0  = kbw[tid];
    int u1i = -1;
    if (tid >= 64 && tid < 256)       u1i = tid - 64;    // waves 1-3 -> 0..191
    else if (tid >= 320 && tid < 384) u1i = tid - 128;   // wave 5    -> 192..255
    float skx1 = 0.f, skh1 = 0.f, bw1 = 0.f;
    if (u1i >= 0) {
        skx1 = strk[2 * 512 + u1i];
        skh1 = strk[2 * 512 + 256 + u1i];
        bw1  = kbw[512 + u1i];
    }

    const float aw0 = aggw[ui], aw1 = aggw[256 + ui], aw2 = aggw[512 + ui], ab = aggb[ui];
    float c_reg = ws_c[b * 256 + ui];

    for (int i = tid; i < 768 * 8; i += 512) ksw_lds[(i >> 3) * 9 + (i & 7)] = ksw[i];
    if (tid < 256) hs[tid] = ws_h[b * 256 + tid];
    if (tid < 256) xs[tid] = X[((size_t)b * T_ + t0) * D_ + tid];
    if (tid < 3)   subs[tid] = ws_sub[b * 3 + tid];
    if (tid < 6)   st2[tid] = stk[tid];

    float az0 = 0.f, az1 = 0.f, az2 = 0.f;     // A(t-1) for gates at CA(tl)
    float xv = 0.f;
    __syncthreads();   // prologue LDS visible (full drain fine, once)

    for (int tl = 0; tl < TC; ++tl) {
        const int t = t0 + tl;

        // ======== phase CA: gates(t-1)+publish | KAN(t) | poll h(t-1) | x(t+1) ========
        if (pstate) {
            if (tl > 0) {
                float z0 = az0, z1 = az1, z2 = az2;
#pragma unroll
                for (int q = 0; q < 4; ++q) {
                    z0 += zred[w + q][lane][0];
                    z1 += zred[w + q][lane][1];
                    z2 += zred[w + q][lane][2];
                }
                float ig = sigm(z0);
                float fg = sigm(z1);
                c_reg = fg * c_reg + ig * tanh_fast(z2);
                float og = sigm(so_l[0] * aw0 + so_l[1] * aw1 + so_l[2] * aw2 + ab);
                float hn = og * tanh_fast(c_reg);
                hs[ui] = hn;
                hhist[tl - 1][c] = hn;
                // sentinel publish of h(s), s = t-1: low mantissa bit := (s>>1)&1.
                // Fire-and-forget: no drain, no flag. Data self-announces.
                unsigned hb = (__float_as_uint(hn) & ~1u) | (unsigned)(((t - 1) >> 1) & 1);
                __hip_atomic_store((unsigned*)&xh[((size_t)b * 2 + ((t - 1) & 1)) * 256 + ui],
                                   hb, __ATOMIC_RELAXED, __HIP_MEMORY_SCOPE_SYSTEM);
            }
            // A(t) prefetch for gates at CA(tl+1)
            const float* Ap = A + ((size_t)b * TC + tl) * TU + ui;
            az0 = Ap[0]; az1 = Ap[256]; az2 = Ap[512];
        }
        if (u1i >= 0) {                           // x(t+1) issue (stage at B)
            int tn = (t + 1 < T_) ? t + 1 : t;
            xv = X[((size_t)b * T_ + tn) * D_ + u1i];
        }
        {                                         // KAN u0 (reads xs(t), subs)
            float a0 = xs[d0] * skx0 + subs[s0] * skh0;
            kred[tid] = a0 * sigm(a0) * bw0 + spline_eval(a0, ksw_lds, tid);
        }
        if (u1i >= 0) {                           // KAN u1
            float a1 = xs[u1i] * skx1 + subs[2] * skh1;
            kred[512 + u1i] = a1 * sigm(a1) * bw1 + spline_eval(a1, ksw_lds, 512 + u1i);
        }
        if (tl > 0 && tid >= 384) {               // waves 6,7: sentinel poll = data fetch
            const int uidx = (1 - r) * 128 + (tid - 384);
            const unsigned expect = (unsigned)(((t - 1) >> 1) & 1);
            const unsigned* src = (const unsigned*)&xh[((size_t)b * 2 + ((t - 1) & 1)) * 256 + uidx];
            unsigned v;
            do {
                v = __hip_atomic_load(src, __ATOMIC_RELAXED, __HIP_MEMORY_SCOPE_SYSTEM);
            } while ((v & 1u) != expect);
            hs[uidx] = __uint_as_float(v);
        }
        BAR_LGKM();   // syncCA: hs(t-1)+kred visible (LDS); vmem stays in flight

        // ======== phase B: GEMV(t) | KAN reduce(t) | stage xs(t+1) ========
        {
            const float* hp = &hs[p * 64];
            float a0 = 0.f, a1 = 0.f, a2 = 0.f;
#pragma unroll
            for (int j = 0; j < 16; ++j) {
                float4 h4 = *(const float4*)(hp + j * 4);   // uniform addr -> LDS broadcast
                a0 = fmaf(h4.x, Rf[0][j * 4 + 0], a0);
                a1 = fmaf(h4.x, Rf[1][j * 4 + 0], a1);
                a2 = fmaf(h4.x, Rf[2][j * 4 + 0], a2);
                a0 = fmaf(h4.y, Rf[0][j * 4 + 1], a0);
                a1 = fmaf(h4.y, Rf[1][j * 4 + 1], a1);
                a2 = fmaf(h4.y, Rf[2][j * 4 + 1], a2);
                a0 = fmaf(h4.z, Rf[0][j * 4 + 2], a0);
                a1 = fmaf(h4.z, Rf[1][j * 4 + 2], a1);
                a2 = fmaf(h4.z, Rf[2][j * 4 + 2], a2);
                a0 = fmaf(h4.w, Rf[0][j * 4 + 3], a0);
                a1 = fmaf(h4.w, Rf[1][j * 4 + 3], a1);
                a2 = fmaf(h4.w, Rf[2][j * 4 + 3], a2);
            }
            zred[w][lane][0] = a0;
            zred[w][lane][1] = a1;
            zred[w][lane][2] = a2;
        }
        if (w < 3) {                              // KAN reduce (kred from syncCA)
            float v = kred[w * 256 + lane] + kred[w * 256 + 64 + lane]
                    + kred[w * 256 + 128 + lane] + kred[w * 256 + 192 + lane];
#pragma unroll
            for (int m = 32; m > 0; m >>= 1) v += __shfl_xor(v, m, 64);
            if (lane == 0) {
                so_l[w] = v;
                subs[w] = st2[w * 2] * v + st2[w * 2 + 1] * subs[w];
            }
        }
        if (u1i >= 0) xs[u1i] = xv;               // stage x(t+1)
        BAR_LGKM();   // syncB: zred/so_l/subs/xs(t+1) visible (LDS)
    }

    // ---- epilogue: final gates (step s = t0+TC-1), then bulk out-write ----
    if (pstate) {
        float z0 = az0, z1 = az1, z2 = az2;       // az = A(t0+TC-1)
#pragma unroll
        for (int q = 0; q < 4; ++q) {
            z0 += zred[w + q][lane][0];
            z1 += zred[w + q][lane][1];
            z2 += zred[w + q][lane][2];
        }
        float ig = sigm(z0);
        float fg = sigm(z1);
        c_reg = fg * c_reg + ig * tanh_fast(z2);
        float og = sigm(so_l[0] * aw0 + so_l[1] * aw1 + so_l[2] * aw2 + ab);
        float hn = og * tanh_fast(c_reg);
        hhist[TC - 1][c] = hn;
        ws_h[b * 256 + ui] = hn;                  // exact value for next chunk's prologue
        ws_c[b * 256 + ui] = c_reg;
        // tagged publish of h(t0+TC-1) keeps per-word tag alternation unbroken
        // across chunk boundaries (R9 fix -- REQUIRED for correctness).
        {
            const int s = t0 + TC - 1;
            unsigned hb = (__float_as_uint(hn) & ~1u) | (unsigned)(((s) >> 1) & 1);
            __hip_atomic_store((unsigned*)&xh[((size_t)b * 2 + (s & 1)) * 256 + ui],
                               hb, __ATOMIC_RELAXED, __HIP_MEMORY_SCOPE_SYSTEM);
        }
    }
    __syncthreads();   // epilogue: full drain fine (once)
    for (int i = tid; i < TC * 128; i += 512) {
        int tl = i >> 7, cc = i & 127;
        out[((size_t)b * T_ + t0 + tl) * U_ + r * 128 + cc] = hhist[tl][cc];
    }
    if (tid < 3) ws_sub[b * 3 + tid] = subs[tid];
}

extern "C" void kernel_launch(void* const* d_in, const int* in_sizes, int n_in,
                              void* d_out, int out_size, void* d_ws, size_t ws_size,
                              hipStream_t stream) {
    const float* x    = (const float*)d_in[0];
    const float* Kmat = (const float*)d_in[1];
    const float* R    = (const float*)d_in[2];
    const float* bias = (const float*)d_in[3];
    const float* stk  = (const float*)d_in[4];
    const float* strk = (const float*)d_in[5];
    const float* aggw = (const float*)d_in[6];
    const float* aggb = (const float*)d_in[7];
    const float* kbw  = (const float*)d_in[8];
    const float* ksw  = (const float*)d_in[9];
    float* out = (float*)d_out;

    float* ws   = (float*)d_ws;
    float* A    = ws;                             // 6,291,456 floats (24 MB)
    float* wh   = A + (size_t)B_ * TC * TU;       // 32768
    float* wc   = wh + B_ * U_;                   // 32768
    float* wsub = wc + B_ * U_;                   // 384 (pad to 512)
    float* xh   = wsub + 512;                     // B*2*256 = 65536

    k0_init<<<dim3(B_), dim3(256), 0, stream>>>(wh, wc, wsub, xh);
    for (int ci = 0; ci < NC; ++ci) {
        k1_gemm<<<dim3((B_ * TC) / 64, TU / 128), dim3(256), 0, stream>>>(x, Kmat, bias, A, ci * TC);
        k2_rec<<<dim3(2 * B_), dim3(512), 0, stream>>>(A, x, R, stk, strk, aggw, aggb, kbw, ksw,
                                                       out, wh, wc, wsub, xh, ci * TC);
    }
}